// Round 1
// baseline (389.579 us; speedup 1.0000x reference)
//
#include <hip/hip_runtime.h>
#include <math.h>

#define T_STEPS 16
#define NTOK 2048
#define WAVES_PER_BLOCK 8
#define BLOCK (WAVES_PER_BLOCK * 64)

// One wave per batch element. Tokens staged in LDS as two float4 arrays:
// ldsA[n] = (x0,y0,x1,y1), ldsB[n] = (x2,y2,x3,y3)  -> dense b128 reads.
__global__ void tokenizer_kernel(const float* __restrict__ data,
                                 const float* __restrict__ tok,
                                 float* __restrict__ out,
                                 int B) {
    __shared__ float4 ldsA[NTOK];
    __shared__ float4 ldsB[NTOK];

    const float4* src = (const float4*)tok;
    for (int j = threadIdx.x; j < 2 * NTOK; j += BLOCK) {
        float4 v = src[j];
        if (j & 1) ldsB[j >> 1] = v;
        else       ldsA[j >> 1] = v;
    }
    __syncthreads();

    const int wave = threadIdx.x >> 6;
    const int lane = threadIdx.x & 63;
    const int b = blockIdx.x * WAVES_PER_BLOCK + wave;
    if (b >= B) return;

    const float* db = data + (size_t)b * (T_STEPS * 3);
    float* outIdx  = out;
    float* outPos  = out + (size_t)B * T_STEPS;
    float* outHead = out + (size_t)B * T_STEPS * 3;

    float cpx = 0.f, cpy = 0.f, chd = 0.f;   // carry: prev_pos, prev_head

    for (int t = 0; t < T_STEPS; ++t) {
        const float px = db[t * 3 + 0];
        const float py = db[t * 3 + 1];
        const float hh = db[t * 3 + 2];

        // gt contour (cal_polygon_contour): order lf, rf, rb, lb
        float sh, ch;
        sincosf(hh, &sh, &ch);
        const float hc = 0.5f * ch, hs = 0.5f * sh;
        const float lc = 4.8f * hc, ls = 4.8f * hs;
        const float wc = 2.0f * hc, ws = 2.0f * hs;
        const float g0x = px + lc - ws, g0y = py + ls + wc;
        const float g1x = px + lc + ws, g1y = py + ls - wc;
        const float g2x = px - lc + ws, g2y = py - ls - wc;
        const float g3x = px - lc - ws, g3y = py - ls + wc;

        // rotation by carry heading
        float rs, rc;
        sincosf(chd, &rs, &rc);

        float bestd = 3.4e38f;
        int   bestn = 0;

        #pragma unroll 4
        for (int k = 0; k < NTOK / 64; ++k) {
            const int n = (k << 6) | lane;
            const float4 A  = ldsA[n];
            const float4 B4 = ldsB[n];

            float d;
            {
                const float twx = A.x * rc - A.y * rs + cpx;
                const float twy = A.x * rs + A.y * rc + cpy;
                const float dx = twx - g0x, dy = twy - g0y;
                d = sqrtf(dx * dx + dy * dy);
            }
            {
                const float twx = A.z * rc - A.w * rs + cpx;
                const float twy = A.z * rs + A.w * rc + cpy;
                const float dx = twx - g1x, dy = twy - g1y;
                d += sqrtf(dx * dx + dy * dy);
            }
            {
                const float twx = B4.x * rc - B4.y * rs + cpx;
                const float twy = B4.x * rs + B4.y * rc + cpy;
                const float dx = twx - g2x, dy = twy - g2y;
                d += sqrtf(dx * dx + dy * dy);
            }
            {
                const float twx = B4.z * rc - B4.w * rs + cpx;
                const float twy = B4.z * rs + B4.w * rc + cpy;
                const float dx = twx - g3x, dy = twy - g3y;
                d += sqrtf(dx * dx + dy * dy);
            }

            if (d < bestd) { bestd = d; bestn = n; }   // strict < keeps lowest n
        }

        // wave argmin reduction, jnp.argmin tie-break (lowest index)
        for (int off = 32; off > 0; off >>= 1) {
            const float od = __shfl_xor(bestd, off, 64);
            const int   on = __shfl_xor(bestn, off, 64);
            if (od < bestd || (od == bestd && on < bestn)) { bestd = od; bestn = on; }
        }

        // selected contour in global frame (same arithmetic path as reference)
        const float4 A  = ldsA[bestn];
        const float4 B4 = ldsB[bestn];
        const float c0x = A.x  * rc - A.y  * rs + cpx, c0y = A.x  * rs + A.y  * rc + cpy;
        const float c1x = A.z  * rc - A.w  * rs + cpx, c1y = A.z  * rs + A.w  * rc + cpy;
        const float c2x = B4.x * rc - B4.y * rs + cpx, c2y = B4.x * rs + B4.y * rc + cpy;
        const float c3x = B4.z * rc - B4.w * rs + cpx, c3y = B4.z * rs + B4.w * rc + cpy;

        const float npx = 0.25f * (((c0x + c1x) + c2x) + c3x);
        const float npy = 0.25f * (((c0y + c1y) + c2y) + c3y);
        const float nh  = atan2f(c0y - c3y, c0x - c3x);

        if (lane == 0) {
            const int ot = b * T_STEPS + t;
            outIdx[ot]          = (float)bestn;
            outPos[2 * ot]      = npx;
            outPos[2 * ot + 1]  = npy;
            outHead[ot]         = nh;
        }

        cpx = npx; cpy = npy; chd = nh;
    }
}

extern "C" void kernel_launch(void* const* d_in, const int* in_sizes, int n_in,
                              void* d_out, int out_size, void* d_ws, size_t ws_size,
                              hipStream_t stream) {
    const float* data = (const float*)d_in[0];
    const float* tok  = (const float*)d_in[1];
    float* out = (float*)d_out;

    const int B = in_sizes[0] / (T_STEPS * 3);   // 4096
    const int grid = (B + WAVES_PER_BLOCK - 1) / WAVES_PER_BLOCK;

    tokenizer_kernel<<<grid, BLOCK, 0, stream>>>(data, tok, out, B);
}

// Round 2
// 149.121 us; speedup vs baseline: 2.6125x; 2.6125x over previous
//
#include <hip/hip_runtime.h>
#include <math.h>

#define T_STEPS 16
#define NTOK 2048
#define WAVES_PER_BLOCK 8
#define BLOCK (WAVES_PER_BLOCK * 64)

// One wave per batch element. Tokens staged in LDS as two float4 arrays:
// ldsA[n] = (x0,y0,x1,y1), ldsB[n] = (x2,y2,x3,y3)  -> dense b128 reads.
__global__ void tokenizer_kernel(const float* __restrict__ data,
                                 const float* __restrict__ tok,
                                 float* __restrict__ out,
                                 int B) {
    __shared__ float4 ldsA[NTOK];
    __shared__ float4 ldsB[NTOK];

    const float4* src = (const float4*)tok;
    for (int j = threadIdx.x; j < 2 * NTOK; j += BLOCK) {
        float4 v = src[j];
        if (j & 1) ldsB[j >> 1] = v;
        else       ldsA[j >> 1] = v;
    }
    __syncthreads();

    const int wave = threadIdx.x >> 6;
    const int lane = threadIdx.x & 63;
    const int b = blockIdx.x * WAVES_PER_BLOCK + wave;
    if (b >= B) return;

    const float* db = data + (size_t)b * (T_STEPS * 3);
    float* outIdx  = out;
    float* outPos  = out + (size_t)B * T_STEPS;
    float* outHead = out + (size_t)B * T_STEPS * 3;

    float cpx = 0.f, cpy = 0.f, chd = 0.f;   // carry: prev_pos, prev_head

    for (int t = 0; t < T_STEPS; ++t) {
        const float px = db[t * 3 + 0];
        const float py = db[t * 3 + 1];
        const float hh = db[t * 3 + 2];

        // gt contour (cal_polygon_contour): order lf, rf, rb, lb
        float sh, ch;
        sincosf(hh, &sh, &ch);
        const float hc = 0.5f * ch, hs = 0.5f * sh;
        const float lc = 4.8f * hc, ls = 4.8f * hs;
        const float wc = 2.0f * hc, ws = 2.0f * hs;

        // rotation by carry heading
        float rs, rc;
        sincosf(chd, &rs, &rc);

        // fold (prev_pos - gt_corner) into per-corner constants:
        // dist_corner = || R*f + (cp - g) ||
        const float e0x = cpx - (px + lc - ws), e0y = cpy - (py + ls + wc);
        const float e1x = cpx - (px + lc + ws), e1y = cpy - (py + ls - wc);
        const float e2x = cpx - (px - lc + ws), e2y = cpy - (py - ls - wc);
        const float e3x = cpx - (px - lc - ws), e3y = cpy - (py - ls + wc);

        float bestd = 3.4e38f;
        int   bestn = 0;

        #pragma unroll 8
        for (int k = 0; k < NTOK / 64; ++k) {
            const int n = (k << 6) | lane;
            const float4 A  = ldsA[n];
            const float4 B4 = ldsB[n];

            float dx, dy, d;
            dx = fmaf(A.x, rc, fmaf(-A.y, rs, e0x));
            dy = fmaf(A.x, rs, fmaf( A.y, rc, e0y));
            d  = __builtin_amdgcn_sqrtf(fmaf(dy, dy, dx * dx));

            dx = fmaf(A.z, rc, fmaf(-A.w, rs, e1x));
            dy = fmaf(A.z, rs, fmaf( A.w, rc, e1y));
            d += __builtin_amdgcn_sqrtf(fmaf(dy, dy, dx * dx));

            dx = fmaf(B4.x, rc, fmaf(-B4.y, rs, e2x));
            dy = fmaf(B4.x, rs, fmaf( B4.y, rc, e2y));
            d += __builtin_amdgcn_sqrtf(fmaf(dy, dy, dx * dx));

            dx = fmaf(B4.z, rc, fmaf(-B4.w, rs, e3x));
            dy = fmaf(B4.z, rs, fmaf( B4.w, rc, e3y));
            d += __builtin_amdgcn_sqrtf(fmaf(dy, dy, dx * dx));

            if (d < bestd) { bestd = d; bestn = n; }   // strict < keeps lowest n
        }

        // wave argmin reduction, jnp.argmin tie-break (lowest index)
        for (int off = 32; off > 0; off >>= 1) {
            const float od = __shfl_xor(bestd, off, 64);
            const int   on = __shfl_xor(bestn, off, 64);
            if (od < bestd || (od == bestd && on < bestn)) { bestd = od; bestn = on; }
        }

        // selected contour in global frame (same arithmetic path as R0-passing version)
        const float4 A  = ldsA[bestn];
        const float4 B4 = ldsB[bestn];
        const float c0x = A.x  * rc - A.y  * rs + cpx, c0y = A.x  * rs + A.y  * rc + cpy;
        const float c1x = A.z  * rc - A.w  * rs + cpx, c1y = A.z  * rs + A.w  * rc + cpy;
        const float c2x = B4.x * rc - B4.y * rs + cpx, c2y = B4.x * rs + B4.y * rc + cpy;
        const float c3x = B4.z * rc - B4.w * rs + cpx, c3y = B4.z * rs + B4.w * rc + cpy;

        const float npx = 0.25f * (((c0x + c1x) + c2x) + c3x);
        const float npy = 0.25f * (((c0y + c1y) + c2y) + c3y);
        const float nh  = atan2f(c0y - c3y, c0x - c3x);

        if (lane == 0) {
            const int ot = b * T_STEPS + t;
            outIdx[ot]          = (float)bestn;
            outPos[2 * ot]      = npx;
            outPos[2 * ot + 1]  = npy;
            outHead[ot]         = nh;
        }

        cpx = npx; cpy = npy; chd = nh;
    }
}

extern "C" void kernel_launch(void* const* d_in, const int* in_sizes, int n_in,
                              void* d_out, int out_size, void* d_ws, size_t ws_size,
                              hipStream_t stream) {
    const float* data = (const float*)d_in[0];
    const float* tok  = (const float*)d_in[1];
    float* out = (float*)d_out;

    const int B = in_sizes[0] / (T_STEPS * 3);   // 4096
    const int grid = (B + WAVES_PER_BLOCK - 1) / WAVES_PER_BLOCK;

    tokenizer_kernel<<<grid, BLOCK, 0, stream>>>(data, tok, out, B);
}